// Round 1
// baseline (101.955 us; speedup 1.0000x reference)
//
#include <hip/hip_runtime.h>
#include <math.h>

#define VOCAB   32000
#define BLTOT   128    // B*L
#define HTOT    64     // H = 8 heads * 8 hph
#define BLT     8      // bl rows accumulated per thread (was 4: halves EV re-stream)
#define VPB     256    // threads per block (4 waves)
#define VT      2      // vocab rows per thread (was 4)
#define SLICE   (VPB * VT)                           // 512 vocab rows per block
#define NSLICE  64                                   // 64*512 = 32768 >= 32000 (tail-guarded)
#define NBLG    (BLTOT / BLT)                        // 16 bl-groups

#define PREP1_BLOCKS 32                              // 8192 threads for f-side
#define PREP2_BLOCKS ((VOCAB * 2 + 255) / 256)       // 250 blocks for EV table

#define LOG2E   1.44269504088896340736f

typedef __fp16 h2 __attribute__((ext_vector_type(2)));

// ---------------------------------------------------------------------------
// Fused prep (unchanged): f-side f16 tables (48 KB) + v-side EV exp table
// (8 MB at ws+49152). exp(-|f-v|) = min(ef*e^-v, emf*e^v).
// ---------------------------------------------------------------------------
__global__ void prep_fused(const float* __restrict__ freqs,
                           const float* __restrict__ amps,
                           const float* __restrict__ phases,
                           const float* __restrict__ ip,
                           const float* __restrict__ W,
                           const float4* __restrict__ vp4,
                           void* __restrict__ ws) {
    if (blockIdx.x < PREP1_BLOCKS) {
        int t = blockIdx.x * blockDim.x + threadIdx.x;   // 0 .. 8191
        int bl = t >> 6;
        int j  = t & 63;
        float fe = freqs[t] * LOG2E;
        float cw = amps[t] * cosf(phases[t] - ip[j]) * W[j >> 3];
        int jj = j >> 2, u = j & 3;
        __fp16* pA = (__fp16*)ws;
        __fp16* pC = (__fp16*)((char*)ws + 32768);
        int ia = (bl * 16 + jj) * 8;
        pA[ia + u]     = (__fp16)__builtin_amdgcn_exp2f(fe);    // e^f
        pA[ia + 4 + u] = (__fp16)__builtin_amdgcn_exp2f(-fe);   // e^-f
        pC[(bl * 16 + jj) * 4 + u] = (__fp16)cw;
    } else {
        int t = (blockIdx.x - PREP1_BLOCKS) * blockDim.x + threadIdx.x;  // 0 .. 63999
        if (t >= VOCAB * 2) return;
        int v   = t >> 1;
        int jj0 = (t & 1) * 8;
        float4* evt4 = (float4*)((char*)ws + 49152);
#pragma unroll
        for (int l = 0; l < 8; ++l) {
            int jj = jj0 + l;
            const float4 vf = vp4[v * 16 + jj];
            float ax = vf.x * LOG2E, ay = vf.y * LOG2E;
            float az = vf.z * LOG2E, aw = vf.w * LOG2E;
            h2 ev01  = __builtin_amdgcn_cvt_pkrtz(__builtin_amdgcn_exp2f( ax),
                                                  __builtin_amdgcn_exp2f( ay));
            h2 ev23  = __builtin_amdgcn_cvt_pkrtz(__builtin_amdgcn_exp2f( az),
                                                  __builtin_amdgcn_exp2f( aw));
            h2 emv01 = __builtin_amdgcn_cvt_pkrtz(__builtin_amdgcn_exp2f(-ax),
                                                  __builtin_amdgcn_exp2f(-ay));
            h2 emv23 = __builtin_amdgcn_cvt_pkrtz(__builtin_amdgcn_exp2f(-az),
                                                  __builtin_amdgcn_exp2f(-aw));
            float4 o;
            o.x = __builtin_bit_cast(float, ev01);
            o.y = __builtin_bit_cast(float, ev23);
            o.z = __builtin_bit_cast(float, emv01);
            o.w = __builtin_bit_cast(float, emv23);
            evt4[jj * VOCAB + v] = o;                    // lane-consecutive in v
        }
    }
}

// ---------------------------------------------------------------------------
// Main, v2: XCD-co-located slices + BLT=8.
//  - 1D grid of 1024 blocks. bid -> {xcd = bid&7, j = bid>>3};
//    slice = xcd + 8*(j>>4), blg = j&15. All 16 bl-group blocks of a slice
//    run on ONE XCD -> per-XCD L2 working set = 8 slices x 128 KB = 1 MB
//    (L2-resident; was 32 x 256 KB = 8 MB > 4 MB L2, thrashing to L3).
//  - BLT=8/VT=2: EV table re-streamed 16x (128 MB L2 traffic) instead of 32x.
//  - Per-thread work unchanged (16 (bl,v) pairs); acc still 16 VGPRs;
//    occupancy still 4 blocks/CU (grid-limited), launch_bounds(256,4).
// ---------------------------------------------------------------------------
__global__ __launch_bounds__(VPB, 4) void
wave_main(const float4* __restrict__ evt4,  // EV table [16][VOCAB]
          const void* __restrict__ uni,     // ws f16 f-side tables
          const float* __restrict__ bptr,   // bias (1 elem)
          float* __restrict__ out) {        // (B*L, VOCAB)
    const int tid = threadIdx.x;
    const int bid = blockIdx.x;             // 0 .. 1023
    const int xcd = bid & 7;
    const int j   = bid >> 3;               // 0 .. 127
    const int slice = xcd + ((j >> 4) << 3);  // 0 .. 63, co-located per XCD
    const int blg   = j & 15;               // 0 .. 15
    const int bl0   = blg * BLT;
    const int v0    = slice * SLICE + tid;

    if (slice * SLICE >= VOCAB) return;     // fully-invalid tail slice (63)

    const float4* gA = (const float4*)((const char*)uni + (size_t)bl0 * 256);
    const float2* gC = (const float2*)((const char*)uni + 32768 + (size_t)bl0 * 128);

    int vidx[VT];
#pragma unroll
    for (int k = 0; k < VT; ++k) {
        int v = v0 + k * VPB;
        vidx[k] = v < VOCAB ? v : VOCAB - 1;   // clamp loads; stores guarded
    }

    float acc[BLT][VT];
#pragma unroll
    for (int i = 0; i < BLT; ++i)
#pragma unroll
        for (int k = 0; k < VT; ++k) acc[i][k] = 0.0f;

#pragma unroll 2
    for (int jj = 0; jj < 16; ++jj) {
        h2 evA[VT], evB[VT], emvA[VT], emvB[VT];
#pragma unroll
        for (int k = 0; k < VT; ++k) {
            const float4 E = evt4[jj * VOCAB + vidx[k]];   // coalesced 16B, L2-hit
            evA[k]  = __builtin_bit_cast(h2, E.x);
            evB[k]  = __builtin_bit_cast(h2, E.y);
            emvA[k] = __builtin_bit_cast(h2, E.z);
            emvB[k] = __builtin_bit_cast(h2, E.w);
        }
#pragma unroll
        for (int i = 0; i < BLT; ++i) {
            const float4 A = gA[i * 16 + jj];         // s_load_dwordx4
            const float2 C = gC[i * 16 + jj];         // s_load_dwordx2
            const h2 ef01 = __builtin_bit_cast(h2, A.x);
            const h2 ef23 = __builtin_bit_cast(h2, A.y);
            const h2 em01 = __builtin_bit_cast(h2, A.z);
            const h2 em23 = __builtin_bit_cast(h2, A.w);
            const h2 cw01 = __builtin_bit_cast(h2, C.x);
            const h2 cw23 = __builtin_bit_cast(h2, C.y);
#pragma unroll
            for (int k = 0; k < VT; ++k) {
                h2 m01 = __builtin_elementwise_min(ef01 * emvA[k], em01 * evA[k]);
                h2 m23 = __builtin_elementwise_min(ef23 * emvB[k], em23 * evB[k]);
                acc[i][k] = __builtin_amdgcn_fdot2(m01, cw01, acc[i][k], false);
                acc[i][k] = __builtin_amdgcn_fdot2(m23, cw23, acc[i][k], false);
            }
        }
    }

    const float b0 = bptr[0];
#pragma unroll
    for (int i = 0; i < BLT; ++i)
#pragma unroll
        for (int k = 0; k < VT; ++k) {
            int v = v0 + k * VPB;
            if (v < VOCAB)
                out[(bl0 + i) * VOCAB + v] = acc[i][k] + b0;   // coalesced per k
        }
}

extern "C" void kernel_launch(void* const* d_in, const int* in_sizes, int n_in,
                              void* d_out, int out_size, void* d_ws, size_t ws_size,
                              hipStream_t stream) {
    const float* freqs  = (const float*)d_in[0];
    const float* amps   = (const float*)d_in[1];
    const float* phases = (const float*)d_in[2];
    const float* vp     = (const float*)d_in[3];
    const float* ip     = (const float*)d_in[4];
    const float* W      = (const float*)d_in[5];
    const float* b      = (const float*)d_in[6];
    float* out = (float*)d_out;

    // 1) fused prep: f-side tables (48 KB) + v-side EV table (8 MB) in one launch
    prep_fused<<<dim3(PREP1_BLOCKS + PREP2_BLOCKS), dim3(256), 0, stream>>>(
        freqs, amps, phases, ip, W, (const float4*)vp, d_ws);

    // 2) main kernel: 1D grid, XCD-co-located vocab slices
    float4* evt4 = (float4*)((char*)d_ws + 49152);
    wave_main<<<dim3(NBLG * NSLICE), dim3(VPB), 0, stream>>>(
        evt4, d_ws, b, out);
}